// Round 4
// baseline (617.599 us; speedup 1.0000x reference)
//
#include <hip/hip_runtime.h>
#include <math.h>

// ManifoldHyperConnect fused kernel.
// Tokens = B*S = 16384, NC = 4096 (N=4 streams x DIM=1024), 24 phi rows.
// One block = 256 threads handles TOK_PER_BLK=4 tokens.
// Thread `tid` owns d-positions [tid*4, tid*4+4) in every stream, so the
// 16 float4 of x it loads serve both the phi-dot phase and the final
// H_res/H_pre/H_post recombination (x read from HBM exactly once).

#define TOK_PER_BLK 4
#define NROWS 24           // 4 pre + 4 post + 16 res
#define NC 4096
#define DIM 1024
#define RMS_EPS 1.1920929e-07f

__device__ __forceinline__ float4 ld4(const float* p) {
    return *reinterpret_cast<const float4*>(p);
}
__device__ __forceinline__ float dot4(float4 a, float4 b) {
    return fmaf(a.x, b.x, fmaf(a.y, b.y, fmaf(a.z, b.z, a.w * b.w)));
}
__device__ __forceinline__ float4 f4mul(float4 a, float4 b) {
    return make_float4(a.x * b.x, a.y * b.y, a.z * b.z, a.w * b.w);
}
__device__ __forceinline__ float4 f4fma(float s, float4 a, float4 b) {
    return make_float4(fmaf(s, a.x, b.x), fmaf(s, a.y, b.y),
                       fmaf(s, a.z, b.z), fmaf(s, a.w, b.w));
}

__global__ __launch_bounds__(256)
void mhc_fused_kernel(const float* __restrict__ x,
                      const float* __restrict__ rms_w,
                      const float* __restrict__ phi_pre,
                      const float* __restrict__ phi_post,
                      const float* __restrict__ phi_res,
                      const float* __restrict__ b_pre,
                      const float* __restrict__ b_post,
                      const float* __restrict__ b_res,
                      const float* __restrict__ a_pre_p,
                      const float* __restrict__ a_post_p,
                      const float* __restrict__ a_res_p,
                      float* __restrict__ out)
{
    const int tid  = threadIdx.x;
    const int wid  = tid >> 6;
    const int lane = tid & 63;
    const int c0   = tid * 4;                       // d-position base (0..1020)
    const long tok0 = (long)blockIdx.x * TOK_PER_BLK;

    __shared__ float ssqp[4][TOK_PER_BLK];          // [wave][token]
    __shared__ float dotp[4][NROWS][TOK_PER_BLK];   // [wave][row][token]
    __shared__ float Hpre_s[TOK_PER_BLK][4];
    __shared__ float Hpost_s[TOK_PER_BLK][4];
    __shared__ float Hres_s[TOK_PER_BLK][16];

    // ---- Phase 1: load x (registers), per-token sum of squares ----
    float4 xr[TOK_PER_BLK][4];
    float ssq[TOK_PER_BLK];
    #pragma unroll
    for (int t = 0; t < TOK_PER_BLK; ++t) {
        const float* xb = x + (tok0 + t) * NC + c0;
        float s = 0.f;
        #pragma unroll
        for (int k = 0; k < 4; ++k) {
            xr[t][k] = ld4(xb + k * DIM);
            s += dot4(xr[t][k], xr[t][k]);
        }
        ssq[t] = s;
    }
    #pragma unroll
    for (int t = 0; t < TOK_PER_BLK; ++t) {
        float s = ssq[t];
        #pragma unroll
        for (int m = 1; m < 64; m <<= 1) s += __shfl_xor(s, m);
        ssq[t] = s;
    }
    if (lane == 0) {
        #pragma unroll
        for (int t = 0; t < TOK_PER_BLK; ++t) ssqp[wid][t] = ssq[t];
    }

    // rms weight for this thread's channels (L2-cached, shared by all blocks)
    float4 w4[4];
    #pragma unroll
    for (int k = 0; k < 4; ++k) w4[k] = ld4(rms_w + k * DIM + c0);

    // ---- Phase 2: 24 dot products dot(x*w, phi_r); rsqrt folded in later ----
    for (int r = 0; r < NROWS; ++r) {
        const float* ph = (r < 4)  ? phi_pre  + r * NC
                        : (r < 8)  ? phi_post + (r - 4) * NC
                                   : phi_res  + (r - 8) * NC;
        float4 q[4];
        #pragma unroll
        for (int k = 0; k < 4; ++k) q[k] = f4mul(w4[k], ld4(ph + k * DIM + c0));

        float acc[TOK_PER_BLK];
        #pragma unroll
        for (int t = 0; t < TOK_PER_BLK; ++t) {
            float a = 0.f;
            #pragma unroll
            for (int k = 0; k < 4; ++k) a += dot4(xr[t][k], q[k]);
            acc[t] = a;
        }
        #pragma unroll
        for (int t = 0; t < TOK_PER_BLK; ++t) {
            float a = acc[t];
            #pragma unroll
            for (int m = 1; m < 64; m <<= 1) a += __shfl_xor(a, m);
            acc[t] = a;
        }
        if (lane == 0) {
            #pragma unroll
            for (int t = 0; t < TOK_PER_BLK; ++t) dotp[wid][r][t] = acc[t];
        }
    }
    __syncthreads();

    // ---- Phase 3: per-wave scalar post-process; wave w owns token w ----
    {
        const int t = wid;
        const float ssqt = ssqp[0][t] + ssqp[1][t] + ssqp[2][t] + ssqp[3][t];
        const float inv = rsqrtf(ssqt * (1.0f / (float)NC) + RMS_EPS);
        if (lane < 16) {
            // Sinkhorn on 4x4; lane = i*4 + j
            float d = dotp[0][8 + lane][t] + dotp[1][8 + lane][t]
                    + dotp[2][8 + lane][t] + dotp[3][8 + lane][t];
            float raw = a_res_p[0] * d * inv + b_res[lane];
            float M = __expf(raw);
            #pragma unroll 1
            for (int it = 0; it < 20; ++it) {
                float rs = M + __shfl_xor(M, 1);   // sum over j (bits 0-1)
                rs += __shfl_xor(rs, 2);
                M = M * __builtin_amdgcn_rcpf(rs + 1e-8f);
                float cs = M + __shfl_xor(M, 4);   // sum over i (bits 2-3)
                cs += __shfl_xor(cs, 8);
                M = M * __builtin_amdgcn_rcpf(cs + 1e-8f);
            }
            Hres_s[t][lane] = M;
        } else if (lane < 24) {
            const int q = lane - 16;               // row 0..7
            float d = dotp[0][q][t] + dotp[1][q][t]
                    + dotp[2][q][t] + dotp[3][q][t];
            if (q < 4) {
                float raw = a_pre_p[0] * d * inv + b_pre[q];
                Hpre_s[t][q] = __builtin_amdgcn_rcpf(1.f + __expf(-raw));
            } else {
                float raw = a_post_p[0] * d * inv + b_post[q - 4];
                Hpost_s[t][q - 4] = 2.f * __builtin_amdgcn_rcpf(1.f + __expf(-raw));
            }
        }
    }
    __syncthreads();

    // ---- Phase 4: out[n,d] = sum_j Hres[n][j] x[j,d] + Hpost[n]*sum_j Hpre[j] x[j,d]
    #pragma unroll
    for (int t = 0; t < TOK_PER_BLK; ++t) {
        const float hp0 = Hpre_s[t][0], hp1 = Hpre_s[t][1];
        const float hp2 = Hpre_s[t][2], hp3 = Hpre_s[t][3];
        float4 li = make_float4(0.f, 0.f, 0.f, 0.f);
        li = f4fma(hp0, xr[t][0], li);
        li = f4fma(hp1, xr[t][1], li);
        li = f4fma(hp2, xr[t][2], li);
        li = f4fma(hp3, xr[t][3], li);
        float* ob = out + (tok0 + t) * NC + c0;
        #pragma unroll
        for (int n = 0; n < 4; ++n) {
            const float h0 = Hres_s[t][n * 4 + 0], h1 = Hres_s[t][n * 4 + 1];
            const float h2 = Hres_s[t][n * 4 + 2], h3 = Hres_s[t][n * 4 + 3];
            const float hq = Hpost_s[t][n];
            float4 o = make_float4(hq * li.x, hq * li.y, hq * li.z, hq * li.w);
            o = f4fma(h0, xr[t][0], o);
            o = f4fma(h1, xr[t][1], o);
            o = f4fma(h2, xr[t][2], o);
            o = f4fma(h3, xr[t][3], o);
            *reinterpret_cast<float4*>(ob + n * DIM) = o;
        }
    }
}

extern "C" void kernel_launch(void* const* d_in, const int* in_sizes, int n_in,
                              void* d_out, int out_size, void* d_ws, size_t ws_size,
                              hipStream_t stream) {
    const float* x        = (const float*)d_in[0];
    const float* rms_w    = (const float*)d_in[1];
    const float* phi_pre  = (const float*)d_in[2];
    const float* phi_post = (const float*)d_in[3];
    const float* phi_res  = (const float*)d_in[4];
    const float* b_pre    = (const float*)d_in[5];
    const float* b_post   = (const float*)d_in[6];
    const float* b_res    = (const float*)d_in[7];
    const float* a_pre    = (const float*)d_in[8];
    const float* a_post   = (const float*)d_in[9];
    const float* a_res    = (const float*)d_in[10];
    float* out = (float*)d_out;

    const int tokens = in_sizes[0] / NC;            // 16384
    const int blocks = tokens / TOK_PER_BLK;        // 4096

    mhc_fused_kernel<<<blocks, 256, 0, stream>>>(
        x, rms_w, phi_pre, phi_post, phi_res,
        b_pre, b_post, b_res, a_pre, a_post, a_res, out);
}

// Round 5
// 533.973 us; speedup vs baseline: 1.1566x; 1.1566x over previous
//
#include <hip/hip_runtime.h>
#include <math.h>

// ManifoldHyperConnect fused kernel, round 5.
// Structure change vs round 4 (which measured 308 us, VALUBusy 22%, HBM 17%,
// i.e. latency-bound on the phase-2 per-(row,token) 6-level shuffle reduces):
//  - Phase 2 now uses a token-distribute butterfly: 3 shuffles/row total
//    (vs 24), leaving each of the 64 lanes with a 4-lane partial for token
//    (lane>>4); all lanes write one float to LDS (conflict-free).
//  - Final 64-partial summation folded into phase 3 (previously idle lanes),
//    via 16B-aligned float4 LDS reads (2-way bank aliasing = free).
//  - ssq handled as "row 24" of the same pipeline; inv broadcast via __shfl.

#define TOK_PER_BLK 4
#define NROWS 24           // 4 pre + 4 post + 16 res
#define NTOT 25            // + ssq as row 24
#define NC 4096
#define DIM 1024
#define RMS_EPS 1.1920929e-07f
#define PADW 68            // padded partial-row stride in floats (68*4B, 16B-aligned)

__device__ __forceinline__ float4 ld4(const float* p) {
    return *reinterpret_cast<const float4*>(p);
}
__device__ __forceinline__ float dot4(float4 a, float4 b) {
    return fmaf(a.x, b.x, fmaf(a.y, b.y, fmaf(a.z, b.z, a.w * b.w)));
}
__device__ __forceinline__ float4 f4mul(float4 a, float4 b) {
    return make_float4(a.x * b.x, a.y * b.y, a.z * b.z, a.w * b.w);
}
__device__ __forceinline__ float4 f4fma(float s, float4 a, float4 b) {
    return make_float4(fmaf(s, a.x, b.x), fmaf(s, a.y, b.y),
                       fmaf(s, a.z, b.z), fmaf(s, a.w, b.w));
}

// Token-distribute butterfly: input a0..a3 = per-lane partials for tokens
// 0..3. Output: one float per lane; lanes [16g,16g+16) hold 4-lane partials
// of token g (sum of the 16 lanes in a group == full 64-lane sum for that
// token). 3 shuffles total.
__device__ __forceinline__ float reduce4(int lane, float a0, float a1,
                                         float a2, float a3) {
    const bool lo = (lane < 32);
    float u = __shfl_xor(lo ? a2 : a0, 32);
    float v = __shfl_xor(lo ? a3 : a1, 32);
    float c = lo ? (a0 + u) : (a2 + u);   // token 2g   partial over {l, l^32}
    float d = lo ? (a1 + v) : (a3 + v);   // token 2g+1 partial over {l, l^32}
    const bool b4 = (lane & 16) != 0;
    float u2 = __shfl_xor(b4 ? c : d, 16);
    return b4 ? (d + u2) : (c + u2);
}

__global__ __launch_bounds__(256, 4)
void mhc_fused_kernel(const float* __restrict__ x,
                      const float* __restrict__ rms_w,
                      const float* __restrict__ phi_pre,
                      const float* __restrict__ phi_post,
                      const float* __restrict__ phi_res,
                      const float* __restrict__ b_pre,
                      const float* __restrict__ b_post,
                      const float* __restrict__ b_res,
                      const float* __restrict__ a_pre_p,
                      const float* __restrict__ a_post_p,
                      const float* __restrict__ a_res_p,
                      float* __restrict__ out)
{
    const int tid  = threadIdx.x;
    const int wid  = tid >> 6;
    const int lane = tid & 63;
    const int c0   = tid * 4;                       // d-position base (0..1020)
    const long tok0 = (long)blockIdx.x * TOK_PER_BLK;

    __shared__ __align__(16) float dotp2[4][NTOT][PADW]; // [wave][row][64 partials]
    __shared__ float Hpre_s[TOK_PER_BLK][4];
    __shared__ float Hpost_s[TOK_PER_BLK][4];
    __shared__ float Hres_s[TOK_PER_BLK][16];

    // ---- Phase 1: load x (registers), per-token ssq partials ----
    float4 xr[TOK_PER_BLK][4];
    float ssq4[TOK_PER_BLK];
    #pragma unroll
    for (int t = 0; t < TOK_PER_BLK; ++t) {
        const float* xb = x + (tok0 + t) * NC + c0;
        float s = 0.f;
        #pragma unroll
        for (int k = 0; k < 4; ++k) {
            xr[t][k] = ld4(xb + k * DIM);
            s += dot4(xr[t][k], xr[t][k]);
        }
        ssq4[t] = s;
    }
    dotp2[wid][24][lane] = reduce4(lane, ssq4[0], ssq4[1], ssq4[2], ssq4[3]);

    // rms weight for this thread's channels (L2-resident, shared by all blocks)
    float4 w4[4];
    #pragma unroll
    for (int k = 0; k < 4; ++k) w4[k] = ld4(rms_w + k * DIM + c0);

    // ---- Phase 2: 24 dot products dot(x, w*phi_r) -> LDS partials ----
    for (int r = 0; r < NROWS; ++r) {
        const float* ph = (r < 4)  ? phi_pre  + r * NC
                        : (r < 8)  ? phi_post + (r - 4) * NC
                                   : phi_res  + (r - 8) * NC;
        float4 q[4];
        #pragma unroll
        for (int k = 0; k < 4; ++k) q[k] = f4mul(w4[k], ld4(ph + k * DIM + c0));

        float a0 = 0.f, a1 = 0.f, a2 = 0.f, a3 = 0.f;
        #pragma unroll
        for (int k = 0; k < 4; ++k) {
            a0 += dot4(xr[0][k], q[k]);
            a1 += dot4(xr[1][k], q[k]);
            a2 += dot4(xr[2][k], q[k]);
            a3 += dot4(xr[3][k], q[k]);
        }
        dotp2[wid][r][lane] = reduce4(lane, a0, a1, a2, a3);
    }
    __syncthreads();

    // ---- Phase 3: per-wave post-process; wave w owns token w ----
    // Lane L sums one row's 64 partials (4 waves x 16 group-t floats):
    //   L in [0,16): res row 8+L ; L in [16,24): pre/post row L-16 ; L==24: ssq.
    if (lane < 25) {
        const int t = wid;
        const int row = (lane < 16) ? (8 + lane)
                      : (lane < 24) ? (lane - 16) : 24;
        float s = 0.f;
        #pragma unroll
        for (int w = 0; w < 4; ++w) {
            #pragma unroll
            for (int j = 0; j < 4; ++j) {
                float4 p = ld4(&dotp2[w][row][16 * t + 4 * j]);
                s += (p.x + p.y) + (p.z + p.w);
            }
        }
        const float ssqt = __shfl(s, 24);
        const float inv = rsqrtf(ssqt * (1.0f / (float)NC) + RMS_EPS);
        if (lane < 16) {
            // Sinkhorn on 4x4; lane = i*4 + j
            float raw = a_res_p[0] * s * inv + b_res[lane];
            float M = __expf(raw);
            #pragma unroll 1
            for (int it = 0; it < 20; ++it) {
                float rs = M + __shfl_xor(M, 1);   // sum over j (bits 0-1)
                rs += __shfl_xor(rs, 2);
                M = M * __builtin_amdgcn_rcpf(rs + 1e-8f);
                float cs = M + __shfl_xor(M, 4);   // sum over i (bits 2-3)
                cs += __shfl_xor(cs, 8);
                M = M * __builtin_amdgcn_rcpf(cs + 1e-8f);
            }
            Hres_s[t][lane] = M;
        } else if (lane < 24) {
            const int q = lane - 16;               // row 0..7
            if (q < 4) {
                float raw = a_pre_p[0] * s * inv + b_pre[q];
                Hpre_s[t][q] = __builtin_amdgcn_rcpf(1.f + __expf(-raw));
            } else {
                float raw = a_post_p[0] * s * inv + b_post[q - 4];
                Hpost_s[t][q - 4] = 2.f * __builtin_amdgcn_rcpf(1.f + __expf(-raw));
            }
        }
    }
    __syncthreads();

    // ---- Phase 4: out[n,d] = sum_j Hres[n][j] x[j,d] + Hpost[n]*sum_j Hpre[j] x[j,d]
    #pragma unroll
    for (int t = 0; t < TOK_PER_BLK; ++t) {
        const float hp0 = Hpre_s[t][0], hp1 = Hpre_s[t][1];
        const float hp2 = Hpre_s[t][2], hp3 = Hpre_s[t][3];
        float4 li = make_float4(0.f, 0.f, 0.f, 0.f);
        li = f4fma(hp0, xr[t][0], li);
        li = f4fma(hp1, xr[t][1], li);
        li = f4fma(hp2, xr[t][2], li);
        li = f4fma(hp3, xr[t][3], li);
        float* ob = out + (tok0 + t) * NC + c0;
        #pragma unroll
        for (int n = 0; n < 4; ++n) {
            const float h0 = Hres_s[t][n * 4 + 0], h1 = Hres_s[t][n * 4 + 1];
            const float h2 = Hres_s[t][n * 4 + 2], h3 = Hres_s[t][n * 4 + 3];
            const float hq = Hpost_s[t][n];
            float4 o = make_float4(hq * li.x, hq * li.y, hq * li.z, hq * li.w);
            o = f4fma(h0, xr[t][0], o);
            o = f4fma(h1, xr[t][1], o);
            o = f4fma(h2, xr[t][2], o);
            o = f4fma(h3, xr[t][3], o);
            *reinterpret_cast<float4*>(ob + n * DIM) = o;
        }
    }
}

extern "C" void kernel_launch(void* const* d_in, const int* in_sizes, int n_in,
                              void* d_out, int out_size, void* d_ws, size_t ws_size,
                              hipStream_t stream) {
    const float* x        = (const float*)d_in[0];
    const float* rms_w    = (const float*)d_in[1];
    const float* phi_pre  = (const float*)d_in[2];
    const float* phi_post = (const float*)d_in[3];
    const float* phi_res  = (const float*)d_in[4];
    const float* b_pre    = (const float*)d_in[5];
    const float* b_post   = (const float*)d_in[6];
    const float* b_res    = (const float*)d_in[7];
    const float* a_pre    = (const float*)d_in[8];
    const float* a_post   = (const float*)d_in[9];
    const float* a_res    = (const float*)d_in[10];
    float* out = (float*)d_out;

    const int tokens = in_sizes[0] / NC;            // 16384
    const int blocks = tokens / TOK_PER_BLK;        // 4096

    mhc_fused_kernel<<<blocks, 256, 0, stream>>>(
        x, rms_w, phi_pre, phi_post, phi_res,
        b_pre, b_post, b_res, a_pre, a_post, a_res, out);
}